// Round 6
// baseline (125.127 us; speedup 1.0000x reference)
//
#include <hip/hip_runtime.h>
#include <math.h>

// Problem constants
#define NB 8
#define NN 128
static constexpr float NEGV = -1000000.0f;

// One workgroup per (b, r). 256 threads = 4 waves. Flash-style online softmax
// over 4 s-tiles of 32. Register tile = 16 INDIVIDUALLY NAMED float4 vars
// (A0..A7 / B0..B7) so nothing can be demoted to scratch (rule #20).
// lane l: e = l>>5, c4 = l&31. Wave w owns s_loc = 8w..8w+7 of each tile.
__global__ __launch_bounds__(256, 4)
void edge_attn_kernel(const float* __restrict__ edge_msgs,
                      const float* __restrict__ node_states,
                      const float* __restrict__ W,
                      const float* __restrict__ bvec,
                      const int*   __restrict__ edges,
                      float* __restrict__ out) {
    const int blk = blockIdx.x;
    const int b = blk >> 7;
    const int r = blk & 127;

    const int t  = threadIdx.x;
    const int w  = t >> 6;       // wave 0..3
    const int l  = t & 63;
    const int e  = l >> 5;       // 0/1
    const int c4 = l & 31;

    // softmax-group identity: group g = sh*2 + se, lane j = s within tile
    const int g  = t >> 5;       // 0..7
    const int j  = t & 31;
    const int se = g & 1;
    const int sh = g >> 1;

    __shared__ float sval[2][32 * 9];    // [parity][s_loc*9 + e*4 + h]
    __shared__ float wtile[2][32 * 9];
    __shared__ float ebias[128 * 2];     // [s*2 + e]
    __shared__ float nodep[4];
    __shared__ float corrbuf[2][8];      // [parity][h*2 + e]
    __shared__ float lbuf[8];            // [h*2 + e]
    __shared__ float outbuf[4][4][128];  // [wave][h][c]

    // ---- W_msg fragment for this lane's c-chunk
    float4 wm0 = *(const float4*)(W +   0 + c4 * 4);
    float4 wm1 = *(const float4*)(W + 256 + c4 * 4);
    float4 wm2 = *(const float4*)(W + 512 + c4 * 4);
    float4 wm3 = *(const float4*)(W + 768 + c4 * 4);

    // ---- stream base for this (b, r): per-s stride = 128*2*128 floats
    const float* bp = edge_msgs
        + (size_t)b * (NN * NN * 256)
        + (size_t)r * 256
        + e * 128 + c4 * 4;

    float4 A0, A1, A2, A3, A4, A5, A6, A7;
    float4 B0, B1, B2, B3, B4, B5, B6, B7;

#define LOADT(V, T)                                                            \
    V##0 = *(const float4*)(bp + (size_t)(32 * (T) + 8 * w + 0) * 32768);      \
    V##1 = *(const float4*)(bp + (size_t)(32 * (T) + 8 * w + 1) * 32768);      \
    V##2 = *(const float4*)(bp + (size_t)(32 * (T) + 8 * w + 2) * 32768);      \
    V##3 = *(const float4*)(bp + (size_t)(32 * (T) + 8 * w + 3) * 32768);      \
    V##4 = *(const float4*)(bp + (size_t)(32 * (T) + 8 * w + 4) * 32768);      \
    V##5 = *(const float4*)(bp + (size_t)(32 * (T) + 8 * w + 5) * 32768);      \
    V##6 = *(const float4*)(bp + (size_t)(32 * (T) + 8 * w + 6) * 32768);      \
    V##7 = *(const float4*)(bp + (size_t)(32 * (T) + 8 * w + 7) * 32768);

    // prologue: issue tile-0 loads immediately
    LOADT(A, 0)

    // ---- node projection: wave 0, 64-lane reduce
    if (w == 0) {
        float2 nv  = *(const float2*)(node_states + ((size_t)b * NN + r) * 128 + l * 2);
        float2 wn0 = *(const float2*)(W + 128 + l * 2);
        float2 wn1 = *(const float2*)(W + 384 + l * 2);
        float2 wn2 = *(const float2*)(W + 640 + l * 2);
        float2 wn3 = *(const float2*)(W + 896 + l * 2);
        float np0 = nv.x * wn0.x + nv.y * wn0.y;
        float np1 = nv.x * wn1.x + nv.y * wn1.y;
        float np2 = nv.x * wn2.x + nv.y * wn2.y;
        float np3 = nv.x * wn3.x + nv.y * wn3.y;
        #pragma unroll
        for (int m = 32; m >= 1; m >>= 1) {
            np0 += __shfl_xor(np0, m);
            np1 += __shfl_xor(np1, m);
            np2 += __shfl_xor(np2, m);
            np3 += __shfl_xor(np3, m);
        }
        if (l == 0) { nodep[0] = np0; nodep[1] = np1; nodep[2] = np2; nodep[3] = np3; }
    }

    // ---- edge mask bias: 256 threads, one int each
    {
        int s  = t >> 1;
        int ec = t & 1;
        int ev = edges[(((size_t)b * NN + s) * NN + r) * 3 + 1 + ec];
        ebias[s * 2 + ec] = (1.0f - (float)ev) * NEGV;
    }
    __syncthreads();

    const float bb = bvec[sh] + nodep[sh];

    float m_run = -INFINITY, l_run = 0.0f;
    float4 a0 = {0,0,0,0}, a1 = {0,0,0,0}, a2 = {0,0,0,0}, a3 = {0,0,0,0};

    const int  hsel = l & 3;
    const bool o1   = (l & 1) != 0;
    const bool o2   = (l & 2) != 0;

#define SCOREV(d, si, P) {                                                     \
    float p0 = d.x * wm0.x + d.y * wm0.y + d.z * wm0.z + d.w * wm0.w;          \
    float p1 = d.x * wm1.x + d.y * wm1.y + d.z * wm1.z + d.w * wm1.w;          \
    float p2 = d.x * wm2.x + d.y * wm2.y + d.z * wm2.z + d.w * wm2.w;          \
    float p3 = d.x * wm3.x + d.y * wm3.y + d.z * wm3.z + d.w * wm3.w;          \
    float x01 = o1 ? p1 : p0, y01 = o1 ? p0 : p1;                              \
    float x23 = o1 ? p3 : p2, y23 = o1 ? p2 : p3;                              \
    float r01 = x01 + __shfl_xor(y01, 1);                                      \
    float r23 = x23 + __shfl_xor(y23, 1);                                      \
    float x2 = o2 ? r23 : r01, y2 = o2 ? r01 : r23;                            \
    float val = x2 + __shfl_xor(y2, 2);                                        \
    val += __shfl_xor(val, 4);                                                 \
    val += __shfl_xor(val, 8);                                                 \
    val += __shfl_xor(val, 16);                                                \
    if ((l & 31) < 4) sval[P][(8 * w + (si)) * 9 + e * 4 + hsel] = val;        \
}

#define AGGV(d, si, P) {                                                       \
    float w0 = wtile[P][(8 * w + (si)) * 9 + e * 4 + 0];                       \
    float w1 = wtile[P][(8 * w + (si)) * 9 + e * 4 + 1];                       \
    float w2 = wtile[P][(8 * w + (si)) * 9 + e * 4 + 2];                       \
    float w3 = wtile[P][(8 * w + (si)) * 9 + e * 4 + 3];                       \
    a0.x += w0 * d.x; a0.y += w0 * d.y; a0.z += w0 * d.z; a0.w += w0 * d.w;    \
    a1.x += w1 * d.x; a1.y += w1 * d.y; a1.z += w1 * d.z; a1.w += w1 * d.w;    \
    a2.x += w2 * d.x; a2.y += w2 * d.y; a2.z += w2 * d.z; a2.w += w2 * d.w;    \
    a3.x += w3 * d.x; a3.y += w3 * d.y; a3.z += w3 * d.z; a3.w += w3 * d.w;    \
}

// One flash tile. P = LDS parity literal, Tl = tile index literal,
// C/N = current/next register-buffer name prefix. Two barriers per tile;
// cross-parity reuse is ordered by the interleaved barriers.
#define TILE(P, Tl, C, N, DOLOAD)                                              \
    if (DOLOAD) { LOADT(N, (Tl) + 1) }                                         \
    SCOREV(C##0, 0, P) SCOREV(C##1, 1, P) SCOREV(C##2, 2, P)                   \
    SCOREV(C##3, 3, P) SCOREV(C##4, 4, P) SCOREV(C##5, 5, P)                   \
    SCOREV(C##6, 6, P) SCOREV(C##7, 7, P)                                      \
    __syncthreads();                                                           \
    {                                                                          \
        float x = sval[P][j * 9 + se * 4 + sh] + bb;                           \
        x = x > 0.f ? x : expm1f(x);                                           \
        float y = x + ebias[(32 * (Tl) + j) * 2 + se];                         \
        float mt = y;                                                          \
        mt = fmaxf(mt, __shfl_xor(mt, 16));                                    \
        mt = fmaxf(mt, __shfl_xor(mt, 8));                                     \
        mt = fmaxf(mt, __shfl_xor(mt, 4));                                     \
        mt = fmaxf(mt, __shfl_xor(mt, 2));                                     \
        mt = fmaxf(mt, __shfl_xor(mt, 1));                                     \
        float m_new = fmaxf(m_run, mt);                                        \
        float corr  = __expf(m_run - m_new);                                   \
        float p     = __expf(y - m_new);                                       \
        float ls = p;                                                          \
        ls += __shfl_xor(ls, 16);                                              \
        ls += __shfl_xor(ls, 8);                                               \
        ls += __shfl_xor(ls, 4);                                               \
        ls += __shfl_xor(ls, 2);                                               \
        ls += __shfl_xor(ls, 1);                                               \
        l_run = l_run * corr + ls;                                             \
        m_run = m_new;                                                         \
        wtile[P][j * 9 + se * 4 + sh] = p;                                     \
        if (j == 0) corrbuf[P][sh * 2 + se] = corr;                            \
    }                                                                          \
    __syncthreads();                                                           \
    {                                                                          \
        float c0 = corrbuf[P][0 * 2 + e];                                      \
        float c1 = corrbuf[P][1 * 2 + e];                                      \
        float c2 = corrbuf[P][2 * 2 + e];                                      \
        float c3 = corrbuf[P][3 * 2 + e];                                      \
        a0.x *= c0; a0.y *= c0; a0.z *= c0; a0.w *= c0;                        \
        a1.x *= c1; a1.y *= c1; a1.z *= c1; a1.w *= c1;                        \
        a2.x *= c2; a2.y *= c2; a2.z *= c2; a2.w *= c2;                        \
        a3.x *= c3; a3.y *= c3; a3.z *= c3; a3.w *= c3;                        \
    }                                                                          \
    AGGV(C##0, 0, P) AGGV(C##1, 1, P) AGGV(C##2, 2, P) AGGV(C##3, 3, P)        \
    AGGV(C##4, 4, P) AGGV(C##5, 5, P) AGGV(C##6, 6, P) AGGV(C##7, 7, P)

    TILE(0, 0, A, B, true)
    TILE(1, 1, B, A, true)
    TILE(0, 2, A, B, true)
    TILE(1, 3, B, A, false)
#undef TILE
#undef SCOREV
#undef AGGV
#undef LOADT

    // ---- final: store l_run, divide, fold e, cross-wave reduce, store
    if (j == 0) lbuf[sh * 2 + se] = l_run;
    __syncthreads();
    {
        float i0 = 1.0f / lbuf[0 * 2 + e];
        float i1 = 1.0f / lbuf[1 * 2 + e];
        float i2 = 1.0f / lbuf[2 * 2 + e];
        float i3 = 1.0f / lbuf[3 * 2 + e];
        a0.x *= i0; a0.y *= i0; a0.z *= i0; a0.w *= i0;
        a1.x *= i1; a1.y *= i1; a1.z *= i1; a1.w *= i1;
        a2.x *= i2; a2.y *= i2; a2.z *= i2; a2.w *= i2;
        a3.x *= i3; a3.y *= i3; a3.z *= i3; a3.w *= i3;
    }
    a0.x += __shfl_xor(a0.x, 32); a0.y += __shfl_xor(a0.y, 32); a0.z += __shfl_xor(a0.z, 32); a0.w += __shfl_xor(a0.w, 32);
    a1.x += __shfl_xor(a1.x, 32); a1.y += __shfl_xor(a1.y, 32); a1.z += __shfl_xor(a1.z, 32); a1.w += __shfl_xor(a1.w, 32);
    a2.x += __shfl_xor(a2.x, 32); a2.y += __shfl_xor(a2.y, 32); a2.z += __shfl_xor(a2.z, 32); a2.w += __shfl_xor(a2.w, 32);
    a3.x += __shfl_xor(a3.x, 32); a3.y += __shfl_xor(a3.y, 32); a3.z += __shfl_xor(a3.z, 32); a3.w += __shfl_xor(a3.w, 32);

    if (e == 0) {
        *(float4*)&outbuf[w][0][c4 * 4] = a0;
        *(float4*)&outbuf[w][1][c4 * 4] = a1;
        *(float4*)&outbuf[w][2][c4 * 4] = a2;
        *(float4*)&outbuf[w][3][c4 * 4] = a3;
    }
    __syncthreads();

    #pragma unroll
    for (int k = 0; k < 2; ++k) {
        int idx = t + 256 * k;          // h*128 + c
        int h = idx >> 7;
        int c = idx & 127;
        float sv = outbuf[0][h][c] + outbuf[1][h][c] + outbuf[2][h][c] + outbuf[3][h][c];
        out[((size_t)b * NN + r) * 512 + idx] = sv;
    }
}

extern "C" void kernel_launch(void* const* d_in, const int* in_sizes, int n_in,
                              void* d_out, int out_size, void* d_ws, size_t ws_size,
                              hipStream_t stream) {
    const float* edge_msgs   = (const float*)d_in[0];
    const float* node_states = (const float*)d_in[1];
    const float* W           = (const float*)d_in[2];
    const float* bvec        = (const float*)d_in[3];
    const int*   edges       = (const int*)d_in[4];
    float* out = (float*)d_out;

    edge_attn_kernel<<<dim3(NB * NN), dim3(256), 0, stream>>>(
        edge_msgs, node_states, W, bvec, edges, out);
}

// Round 7
// 62.357 us; speedup vs baseline: 2.0066x; 2.0066x over previous
//
#include <hip/hip_runtime.h>
#include <math.h>

// Problem constants
#define NB 8
#define NN 128
static constexpr float NEGV = -1000000.0f;

// One workgroup per (b, r). 256 threads = 4 waves. Flash-style online softmax
// over 4 s-tiles of 32. Register tile = 16 individually named float4 vars.
// NOTE: no min-waves arg in __launch_bounds__ — hipcc caps VGPRs at
// 256/min_waves (R4-R6: arg=4 -> 64-VGPR cap -> massive scratch spill).
// lane l: e = l>>5, c4 = l&31. Wave w owns s_loc = 8w..8w+7 of each tile.
__global__ __launch_bounds__(256)
void edge_attn_kernel(const float* __restrict__ edge_msgs,
                      const float* __restrict__ node_states,
                      const float* __restrict__ W,
                      const float* __restrict__ bvec,
                      const int*   __restrict__ edges,
                      float* __restrict__ out) {
    const int blk = blockIdx.x;
    const int b = blk >> 7;
    const int r = blk & 127;

    const int t  = threadIdx.x;
    const int w  = t >> 6;       // wave 0..3
    const int l  = t & 63;
    const int e  = l >> 5;       // 0/1
    const int c4 = l & 31;

    // softmax-group identity: group g = sh*2 + se, lane j = s within tile
    const int g  = t >> 5;       // 0..7
    const int j  = t & 31;
    const int se = g & 1;
    const int sh = g >> 1;

    __shared__ float sval[2][32 * 9];    // [parity][s_loc*9 + e*4 + h]
    __shared__ float wtile[2][32 * 9];
    __shared__ float ebias[128 * 2];     // [s*2 + e]
    __shared__ float nodep[4];
    __shared__ float corrbuf[2][8];      // [parity][h*2 + e]
    __shared__ float lbuf[8];            // [h*2 + e]
    __shared__ float outbuf[4][4][128];  // [wave][h][c]

    // ---- W_msg fragment for this lane's c-chunk
    float4 wm0 = *(const float4*)(W +   0 + c4 * 4);
    float4 wm1 = *(const float4*)(W + 256 + c4 * 4);
    float4 wm2 = *(const float4*)(W + 512 + c4 * 4);
    float4 wm3 = *(const float4*)(W + 768 + c4 * 4);

    // ---- stream base for this (b, r): per-s stride = 128*2*128 floats
    const float* bp = edge_msgs
        + (size_t)b * (NN * NN * 256)
        + (size_t)r * 256
        + e * 128 + c4 * 4;

    float4 A0, A1, A2, A3, A4, A5, A6, A7;
    float4 B0, B1, B2, B3, B4, B5, B6, B7;

#define LOADT(V, T)                                                            \
    V##0 = *(const float4*)(bp + (size_t)(32 * (T) + 8 * w + 0) * 32768);      \
    V##1 = *(const float4*)(bp + (size_t)(32 * (T) + 8 * w + 1) * 32768);      \
    V##2 = *(const float4*)(bp + (size_t)(32 * (T) + 8 * w + 2) * 32768);      \
    V##3 = *(const float4*)(bp + (size_t)(32 * (T) + 8 * w + 3) * 32768);      \
    V##4 = *(const float4*)(bp + (size_t)(32 * (T) + 8 * w + 4) * 32768);      \
    V##5 = *(const float4*)(bp + (size_t)(32 * (T) + 8 * w + 5) * 32768);      \
    V##6 = *(const float4*)(bp + (size_t)(32 * (T) + 8 * w + 6) * 32768);      \
    V##7 = *(const float4*)(bp + (size_t)(32 * (T) + 8 * w + 7) * 32768);

    // prologue: issue tile-0 loads immediately
    LOADT(A, 0)

    // ---- node projection: wave 0, 64-lane reduce
    if (w == 0) {
        float2 nv  = *(const float2*)(node_states + ((size_t)b * NN + r) * 128 + l * 2);
        float2 wn0 = *(const float2*)(W + 128 + l * 2);
        float2 wn1 = *(const float2*)(W + 384 + l * 2);
        float2 wn2 = *(const float2*)(W + 640 + l * 2);
        float2 wn3 = *(const float2*)(W + 896 + l * 2);
        float np0 = nv.x * wn0.x + nv.y * wn0.y;
        float np1 = nv.x * wn1.x + nv.y * wn1.y;
        float np2 = nv.x * wn2.x + nv.y * wn2.y;
        float np3 = nv.x * wn3.x + nv.y * wn3.y;
        #pragma unroll
        for (int m = 32; m >= 1; m >>= 1) {
            np0 += __shfl_xor(np0, m);
            np1 += __shfl_xor(np1, m);
            np2 += __shfl_xor(np2, m);
            np3 += __shfl_xor(np3, m);
        }
        if (l == 0) { nodep[0] = np0; nodep[1] = np1; nodep[2] = np2; nodep[3] = np3; }
    }

    // ---- edge mask bias: 256 threads, one int each
    {
        int s  = t >> 1;
        int ec = t & 1;
        int ev = edges[(((size_t)b * NN + s) * NN + r) * 3 + 1 + ec];
        ebias[s * 2 + ec] = (1.0f - (float)ev) * NEGV;
    }
    __syncthreads();

    const float bb = bvec[sh] + nodep[sh];

    float m_run = -INFINITY, l_run = 0.0f;
    float4 a0 = {0,0,0,0}, a1 = {0,0,0,0}, a2 = {0,0,0,0}, a3 = {0,0,0,0};

    const int  hsel = l & 3;
    const bool o1   = (l & 1) != 0;
    const bool o2   = (l & 2) != 0;

#define SCOREV(d, si, P) {                                                     \
    float p0 = d.x * wm0.x + d.y * wm0.y + d.z * wm0.z + d.w * wm0.w;          \
    float p1 = d.x * wm1.x + d.y * wm1.y + d.z * wm1.z + d.w * wm1.w;          \
    float p2 = d.x * wm2.x + d.y * wm2.y + d.z * wm2.z + d.w * wm2.w;          \
    float p3 = d.x * wm3.x + d.y * wm3.y + d.z * wm3.z + d.w * wm3.w;          \
    float x01 = o1 ? p1 : p0, y01 = o1 ? p0 : p1;                              \
    float x23 = o1 ? p3 : p2, y23 = o1 ? p2 : p3;                              \
    float r01 = x01 + __shfl_xor(y01, 1);                                      \
    float r23 = x23 + __shfl_xor(y23, 1);                                      \
    float x2 = o2 ? r23 : r01, y2 = o2 ? r01 : r23;                            \
    float val = x2 + __shfl_xor(y2, 2);                                        \
    val += __shfl_xor(val, 4);                                                 \
    val += __shfl_xor(val, 8);                                                 \
    val += __shfl_xor(val, 16);                                                \
    if ((l & 31) < 4) sval[P][(8 * w + (si)) * 9 + e * 4 + hsel] = val;        \
}

#define AGGV(d, si, P) {                                                       \
    float w0 = wtile[P][(8 * w + (si)) * 9 + e * 4 + 0];                       \
    float w1 = wtile[P][(8 * w + (si)) * 9 + e * 4 + 1];                       \
    float w2 = wtile[P][(8 * w + (si)) * 9 + e * 4 + 2];                       \
    float w3 = wtile[P][(8 * w + (si)) * 9 + e * 4 + 3];                       \
    a0.x += w0 * d.x; a0.y += w0 * d.y; a0.z += w0 * d.z; a0.w += w0 * d.w;    \
    a1.x += w1 * d.x; a1.y += w1 * d.y; a1.z += w1 * d.z; a1.w += w1 * d.w;    \
    a2.x += w2 * d.x; a2.y += w2 * d.y; a2.z += w2 * d.z; a2.w += w2 * d.w;    \
    a3.x += w3 * d.x; a3.y += w3 * d.y; a3.z += w3 * d.z; a3.w += w3 * d.w;    \
}

// One flash tile. P = LDS parity literal, Tl = tile index literal,
// C/N = current/next register-buffer name prefix. Two barriers per tile;
// cross-parity reuse is ordered by the interleaved barriers.
#define TILE(P, Tl, C, N, DOLOAD)                                              \
    if (DOLOAD) { LOADT(N, (Tl) + 1) }                                         \
    SCOREV(C##0, 0, P) SCOREV(C##1, 1, P) SCOREV(C##2, 2, P)                   \
    SCOREV(C##3, 3, P) SCOREV(C##4, 4, P) SCOREV(C##5, 5, P)                   \
    SCOREV(C##6, 6, P) SCOREV(C##7, 7, P)                                      \
    __syncthreads();                                                           \
    {                                                                          \
        float x = sval[P][j * 9 + se * 4 + sh] + bb;                           \
        x = x > 0.f ? x : expm1f(x);                                           \
        float y = x + ebias[(32 * (Tl) + j) * 2 + se];                         \
        float mt = y;                                                          \
        mt = fmaxf(mt, __shfl_xor(mt, 16));                                    \
        mt = fmaxf(mt, __shfl_xor(mt, 8));                                     \
        mt = fmaxf(mt, __shfl_xor(mt, 4));                                     \
        mt = fmaxf(mt, __shfl_xor(mt, 2));                                     \
        mt = fmaxf(mt, __shfl_xor(mt, 1));                                     \
        float m_new = fmaxf(m_run, mt);                                        \
        float corr  = __expf(m_run - m_new);                                   \
        float p     = __expf(y - m_new);                                       \
        float ls = p;                                                          \
        ls += __shfl_xor(ls, 16);                                              \
        ls += __shfl_xor(ls, 8);                                               \
        ls += __shfl_xor(ls, 4);                                               \
        ls += __shfl_xor(ls, 2);                                               \
        ls += __shfl_xor(ls, 1);                                               \
        l_run = l_run * corr + ls;                                             \
        m_run = m_new;                                                         \
        wtile[P][j * 9 + se * 4 + sh] = p;                                     \
        if (j == 0) corrbuf[P][sh * 2 + se] = corr;                            \
    }                                                                          \
    __syncthreads();                                                           \
    {                                                                          \
        float c0 = corrbuf[P][0 * 2 + e];                                      \
        float c1 = corrbuf[P][1 * 2 + e];                                      \
        float c2 = corrbuf[P][2 * 2 + e];                                      \
        float c3 = corrbuf[P][3 * 2 + e];                                      \
        a0.x *= c0; a0.y *= c0; a0.z *= c0; a0.w *= c0;                        \
        a1.x *= c1; a1.y *= c1; a1.z *= c1; a1.w *= c1;                        \
        a2.x *= c2; a2.y *= c2; a2.z *= c2; a2.w *= c2;                        \
        a3.x *= c3; a3.y *= c3; a3.z *= c3; a3.w *= c3;                        \
    }                                                                          \
    AGGV(C##0, 0, P) AGGV(C##1, 1, P) AGGV(C##2, 2, P) AGGV(C##3, 3, P)        \
    AGGV(C##4, 4, P) AGGV(C##5, 5, P) AGGV(C##6, 6, P) AGGV(C##7, 7, P)

    TILE(0, 0, A, B, true)
    TILE(1, 1, B, A, true)
    TILE(0, 2, A, B, true)
    TILE(1, 3, B, A, false)
#undef TILE
#undef SCOREV
#undef AGGV
#undef LOADT

    // ---- final: store l_run, divide, fold e, cross-wave reduce, store
    if (j == 0) lbuf[sh * 2 + se] = l_run;
    __syncthreads();
    {
        float i0 = 1.0f / lbuf[0 * 2 + e];
        float i1 = 1.0f / lbuf[1 * 2 + e];
        float i2 = 1.0f / lbuf[2 * 2 + e];
        float i3 = 1.0f / lbuf[3 * 2 + e];
        a0.x *= i0; a0.y *= i0; a0.z *= i0; a0.w *= i0;
        a1.x *= i1; a1.y *= i1; a1.z *= i1; a1.w *= i1;
        a2.x *= i2; a2.y *= i2; a2.z *= i2; a2.w *= i2;
        a3.x *= i3; a3.y *= i3; a3.z *= i3; a3.w *= i3;
    }
    a0.x += __shfl_xor(a0.x, 32); a0.y += __shfl_xor(a0.y, 32); a0.z += __shfl_xor(a0.z, 32); a0.w += __shfl_xor(a0.w, 32);
    a1.x += __shfl_xor(a1.x, 32); a1.y += __shfl_xor(a1.y, 32); a1.z += __shfl_xor(a1.z, 32); a1.w += __shfl_xor(a1.w, 32);
    a2.x += __shfl_xor(a2.x, 32); a2.y += __shfl_xor(a2.y, 32); a2.z += __shfl_xor(a2.z, 32); a2.w += __shfl_xor(a2.w, 32);
    a3.x += __shfl_xor(a3.x, 32); a3.y += __shfl_xor(a3.y, 32); a3.z += __shfl_xor(a3.z, 32); a3.w += __shfl_xor(a3.w, 32);

    if (e == 0) {
        *(float4*)&outbuf[w][0][c4 * 4] = a0;
        *(float4*)&outbuf[w][1][c4 * 4] = a1;
        *(float4*)&outbuf[w][2][c4 * 4] = a2;
        *(float4*)&outbuf[w][3][c4 * 4] = a3;
    }
    __syncthreads();

    #pragma unroll
    for (int k = 0; k < 2; ++k) {
        int idx = t + 256 * k;          // h*128 + c
        int h = idx >> 7;
        int c = idx & 127;
        float sv = outbuf[0][h][c] + outbuf[1][h][c] + outbuf[2][h][c] + outbuf[3][h][c];
        out[((size_t)b * NN + r) * 512 + idx] = sv;
    }
}

extern "C" void kernel_launch(void* const* d_in, const int* in_sizes, int n_in,
                              void* d_out, int out_size, void* d_ws, size_t ws_size,
                              hipStream_t stream) {
    const float* edge_msgs   = (const float*)d_in[0];
    const float* node_states = (const float*)d_in[1];
    const float* W           = (const float*)d_in[2];
    const float* bvec        = (const float*)d_in[3];
    const int*   edges       = (const int*)d_in[4];
    float* out = (float*)d_out;

    edge_attn_kernel<<<dim3(NB * NN), dim3(256), 0, stream>>>(
        edge_msgs, node_states, W, bvec, edges, out);
}

// Round 9
// 32.149 us; speedup vs baseline: 3.8920x; 1.9396x over previous
//
#include <hip/hip_runtime.h>
#include <math.h>

// Problem constants
#define NB 8
#define NN 128
static constexpr float NEGV = -1000000.0f;

// One workgroup per (b, r). 512 threads = 8 waves. R2 structure (single
// 16-deep load batch -> max MLP, quad-partial scores, one softmax phase,
// register-resident aggregation) with:
//  - __launch_bounds__(512) ONLY: no min-waves arg (R4-R6 lesson: arg w
//    caps VGPRs at 256/w and induces silent scratch spill).
//  - tile in 16 individually named float4s (no array -> no SROA demotion).
//  - R8 bugfix: wts sized 2*128*5 (was 128*5; e=1 half ran out of bounds).
// lane l: e = l>>5, c4 = l&31. Wave w owns s = w + 8*si, si=0..15.
__global__ __launch_bounds__(512)
void edge_attn_kernel(const float* __restrict__ edge_msgs,
                      const float* __restrict__ node_states,
                      const float* __restrict__ W,
                      const float* __restrict__ bvec,
                      const int*   __restrict__ edges,
                      float* __restrict__ out) {
    const int blk = blockIdx.x;
    const int b = blk >> 7;
    const int r = blk & 127;

    const int t  = threadIdx.x;
    const int w  = t >> 6;      // wave 0..7
    const int l  = t & 63;
    const int e  = l >> 5;      // 0/1
    const int c4 = l & 31;

    // part: per s (stride 68 floats): [e*32 + h*8 + g] = quad-partial
    __shared__ float part[128 * 68];
    __shared__ float wts [2 * 128 * 5];  // [e*640 + s*5 + h] softmax weights
    __shared__ float ebias[128 * 2];     // [s*2 + e]
    __shared__ float nodep[4];
    __shared__ float outbuf[8][4][128];  // [wave][h][c]

    // ---- W_msg fragment for this lane's c-chunk
    float4 wm0 = *(const float4*)(W +   0 + c4 * 4);
    float4 wm1 = *(const float4*)(W + 256 + c4 * 4);
    float4 wm2 = *(const float4*)(W + 512 + c4 * 4);
    float4 wm3 = *(const float4*)(W + 768 + c4 * 4);

    // ---- stream base for this (b, r): per-s stride = 32768 floats
    const float* bp = edge_msgs
        + (size_t)b * (NN * NN * 256)
        + (size_t)r * 256
        + e * 128 + c4 * 4;

    float4 V0, V1, V2, V3, V4, V5, V6, V7, V8, V9, V10, V11, V12, V13, V14, V15;

#define LOADV(i) V##i = *(const float4*)(bp + (size_t)(w + 8 * (i)) * 32768);
    LOADV(0)  LOADV(1)  LOADV(2)  LOADV(3)
    LOADV(4)  LOADV(5)  LOADV(6)  LOADV(7)
    LOADV(8)  LOADV(9)  LOADV(10) LOADV(11)
    LOADV(12) LOADV(13) LOADV(14) LOADV(15)
#undef LOADV

    // ---- node projection: wave 0 only, 64-lane reduce
    if (w == 0) {
        float2 nv  = *(const float2*)(node_states + ((size_t)b * NN + r) * 128 + l * 2);
        float2 wn0 = *(const float2*)(W + 128 + l * 2);
        float2 wn1 = *(const float2*)(W + 384 + l * 2);
        float2 wn2 = *(const float2*)(W + 640 + l * 2);
        float2 wn3 = *(const float2*)(W + 896 + l * 2);
        float np0 = nv.x * wn0.x + nv.y * wn0.y;
        float np1 = nv.x * wn1.x + nv.y * wn1.y;
        float np2 = nv.x * wn2.x + nv.y * wn2.y;
        float np3 = nv.x * wn3.x + nv.y * wn3.y;
        #pragma unroll
        for (int m = 32; m >= 1; m >>= 1) {
            np0 += __shfl_xor(np0, m);
            np1 += __shfl_xor(np1, m);
            np2 += __shfl_xor(np2, m);
            np3 += __shfl_xor(np3, m);
        }
        if (l == 0) { nodep[0] = np0; nodep[1] = np1; nodep[2] = np2; nodep[3] = np3; }
    }

    // ---- edge mask bias: first 256 threads load one int each
    if (t < 256) {
        int s  = t >> 1;
        int ec = t & 1;
        int ev = edges[(((size_t)b * NN + s) * NN + r) * 3 + 1 + ec];
        ebias[s * 2 + ec] = (1.0f - (float)ev) * NEGV;
    }

    // ---- Pass A: quad-partial scores. 3 shuffles + 1 LDS store per si.
    const int hsel = l & 3;
    const int g    = (l >> 2) & 7;
    const bool o1  = (l & 1) != 0;
    const bool o2  = (l & 2) != 0;

#define SCOREV(d, si) {                                                        \
    float p0 = d.x * wm0.x + d.y * wm0.y + d.z * wm0.z + d.w * wm0.w;          \
    float p1 = d.x * wm1.x + d.y * wm1.y + d.z * wm1.z + d.w * wm1.w;          \
    float p2 = d.x * wm2.x + d.y * wm2.y + d.z * wm2.z + d.w * wm2.w;          \
    float p3 = d.x * wm3.x + d.y * wm3.y + d.z * wm3.z + d.w * wm3.w;          \
    float x01 = o1 ? p1 : p0, y01 = o1 ? p0 : p1;                              \
    float x23 = o1 ? p3 : p2, y23 = o1 ? p2 : p3;                              \
    float r01 = x01 + __shfl_xor(y01, 1);                                      \
    float r23 = x23 + __shfl_xor(y23, 1);                                      \
    float x2 = o2 ? r23 : r01, y2 = o2 ? r01 : r23;                            \
    float val = x2 + __shfl_xor(y2, 2);                                        \
    part[(w + 8 * (si)) * 68 + e * 32 + hsel * 8 + g] = val;                   \
}
    SCOREV(V0, 0)   SCOREV(V1, 1)   SCOREV(V2, 2)   SCOREV(V3, 3)
    SCOREV(V4, 4)   SCOREV(V5, 5)   SCOREV(V6, 6)   SCOREV(V7, 7)
    SCOREV(V8, 8)   SCOREV(V9, 9)   SCOREV(V10, 10) SCOREV(V11, 11)
    SCOREV(V12, 12) SCOREV(V13, 13) SCOREV(V14, 14) SCOREV(V15, 15)
#undef SCOREV
    __syncthreads();

    // ---- Softmax over s per (e,h): 8 groups x 32 lanes (first 256 threads)
    if (t < 256) {
        int p  = t >> 5;        // 0..7
        int j  = t & 31;
        int es = p & 1;
        int h  = p >> 1;
        float bb = bvec[h] + nodep[h];
        float y0, y1, y2, y3;
        #define SCORE(k, dst)                                                  \
        {                                                                      \
            int s = j + 32 * k;                                                \
            const float* q = &part[s * 68 + es * 32 + h * 8];                  \
            float4 qa = *(const float4*)q;                                     \
            float4 qb = *(const float4*)(q + 4);                               \
            float x = (qa.x + qa.y + qa.z + qa.w)                              \
                    + (qb.x + qb.y + qb.z + qb.w) + bb;                        \
            x = x > 0.f ? x : expm1f(x);                                       \
            dst = x + ebias[s * 2 + es];                                       \
        }
        SCORE(0, y0) SCORE(1, y1) SCORE(2, y2) SCORE(3, y3)
        #undef SCORE
        float m4 = fmaxf(fmaxf(y0, y1), fmaxf(y2, y3));
        #pragma unroll
        for (int m = 16; m >= 1; m >>= 1) m4 = fmaxf(m4, __shfl_xor(m4, m));
        y0 = __expf(y0 - m4); y1 = __expf(y1 - m4);
        y2 = __expf(y2 - m4); y3 = __expf(y3 - m4);
        float sum = y0 + y1 + y2 + y3;
        #pragma unroll
        for (int m = 16; m >= 1; m >>= 1) sum += __shfl_xor(sum, m);
        float inv = 1.0f / sum;
        wts[es * 640 + (j +  0) * 5 + h] = y0 * inv;
        wts[es * 640 + (j + 32) * 5 + h] = y1 * inv;
        wts[es * 640 + (j + 64) * 5 + h] = y2 * inv;
        wts[es * 640 + (j + 96) * 5 + h] = y3 * inv;
    }
    __syncthreads();

    // ---- Pass B: weighted aggregation from register-resident tile
    float4 a0 = {0,0,0,0}, a1 = {0,0,0,0}, a2 = {0,0,0,0}, a3 = {0,0,0,0};
#define AGGV(d, si) {                                                          \
    int s = w + 8 * (si);                                                      \
    float w0 = wts[e * 640 + s * 5 + 0];                                       \
    float w1 = wts[e * 640 + s * 5 + 1];                                       \
    float w2 = wts[e * 640 + s * 5 + 2];                                       \
    float w3 = wts[e * 640 + s * 5 + 3];                                       \
    a0.x += w0 * d.x; a0.y += w0 * d.y; a0.z += w0 * d.z; a0.w += w0 * d.w;    \
    a1.x += w1 * d.x; a1.y += w1 * d.y; a1.z += w1 * d.z; a1.w += w1 * d.w;    \
    a2.x += w2 * d.x; a2.y += w2 * d.y; a2.z += w2 * d.z; a2.w += w2 * d.w;    \
    a3.x += w3 * d.x; a3.y += w3 * d.y; a3.z += w3 * d.z; a3.w += w3 * d.w;    \
}
    AGGV(V0, 0)   AGGV(V1, 1)   AGGV(V2, 2)   AGGV(V3, 3)
    AGGV(V4, 4)   AGGV(V5, 5)   AGGV(V6, 6)   AGGV(V7, 7)
    AGGV(V8, 8)   AGGV(V9, 9)   AGGV(V10, 10) AGGV(V11, 11)
    AGGV(V12, 12) AGGV(V13, 13) AGGV(V14, 14) AGGV(V15, 15)
#undef AGGV

    // fold the two e halves: lane l and l^32 hold the same c4
    a0.x += __shfl_xor(a0.x, 32); a0.y += __shfl_xor(a0.y, 32); a0.z += __shfl_xor(a0.z, 32); a0.w += __shfl_xor(a0.w, 32);
    a1.x += __shfl_xor(a1.x, 32); a1.y += __shfl_xor(a1.y, 32); a1.z += __shfl_xor(a1.z, 32); a1.w += __shfl_xor(a1.w, 32);
    a2.x += __shfl_xor(a2.x, 32); a2.y += __shfl_xor(a2.y, 32); a2.z += __shfl_xor(a2.z, 32); a2.w += __shfl_xor(a2.w, 32);
    a3.x += __shfl_xor(a3.x, 32); a3.y += __shfl_xor(a3.y, 32); a3.z += __shfl_xor(a3.z, 32); a3.w += __shfl_xor(a3.w, 32);

    if (e == 0) {
        *(float4*)&outbuf[w][0][c4 * 4] = a0;
        *(float4*)&outbuf[w][1][c4 * 4] = a1;
        *(float4*)&outbuf[w][2][c4 * 4] = a2;
        *(float4*)&outbuf[w][3][c4 * 4] = a3;
    }
    __syncthreads();

    // ---- cross-wave reduce + coalesced store: t = h*128 + c
    {
        int h = t >> 7;
        int c = t & 127;
        float sv = 0.f;
        #pragma unroll
        for (int k = 0; k < 8; ++k) sv += outbuf[k][h][c];
        out[((size_t)b * NN + r) * 512 + t] = sv;
    }
}

extern "C" void kernel_launch(void* const* d_in, const int* in_sizes, int n_in,
                              void* d_out, int out_size, void* d_ws, size_t ws_size,
                              hipStream_t stream) {
    const float* edge_msgs   = (const float*)d_in[0];
    const float* node_states = (const float*)d_in[1];
    const float* W           = (const float*)d_in[2];
    const float* bvec        = (const float*)d_in[3];
    const int*   edges       = (const int*)d_in[4];
    float* out = (float*)d_out;

    dim3 grid(NB * NN);
    dim3 block(512);
    edge_attn_kernel<<<grid, block, 0, stream>>>(edge_msgs, node_states, W, bvec, edges, out);
}